// Round 3
// baseline (23612.582 us; speedup 1.0000x reference)
//
#include <hip/hip_runtime.h>
#include <cstdint>
#include <cstddef>

// ---------------------------------------------------------------------------
// MyLSTM on MI355X.
// Phase 1: xg[B*T,4H] = x @ W + bias  (bf16 MFMA 16x16x32, 128x128 tiles)
// Phase 2: weight-stationary persistent recurrence:
//   64 blocks x 512 threads (plain launch; 64 blocks on 256 CUs are
//   co-resident), block owns 8 hidden units (32 gate cols). R-slice
//   register-resident (16 B-frags/wave). Per step: read broadcast h
//   (bf16 hi+lo pair ~= fp32), z = h @ Rslice via MFMA, gates for owned
//   units (c in regs), publish h-slice; device-scope release-fence + flag,
//   relaxed-spin + one acquire-fence = per-step barrier. h double-buffered.
// Gate layout along 4H: [i, f, g, o].
// ---------------------------------------------------------------------------

typedef __attribute__((ext_vector_type(8))) __bf16 bf16x8;
typedef __attribute__((ext_vector_type(4))) float floatx4;

__device__ __forceinline__ unsigned short f2bf(float f) {
  union { float f; uint32_t u; } v; v.f = f;
  uint32_t u = v.u;
  uint32_t r = (u + 0x7fffu + ((u >> 16) & 1u)) >> 16;  // RNE
  return (unsigned short)r;
}
__device__ __forceinline__ float bflo(uint32_t u) {
  union { uint32_t u; float f; } v; v.u = u << 16; return v.f;
}
__device__ __forceinline__ float bfhi(uint32_t u) {
  union { uint32_t u; float f; } v; v.u = u & 0xffff0000u; return v.f;
}
__device__ __forceinline__ float bf2f(unsigned short s) {
  union { uint32_t u; float f; } v; v.u = ((uint32_t)s) << 16; return v.f;
}

// ---------------------------- converters -----------------------------------

__global__ void cvt_x_kernel(const float4* __restrict__ x, uint2* __restrict__ xbf, int n4) {
  int stride = gridDim.x * blockDim.x;
  for (int i = blockIdx.x * blockDim.x + threadIdx.x; i < n4; i += stride) {
    float4 v = x[i];
    uint2 o;
    o.x = (uint32_t)f2bf(v.x) | ((uint32_t)f2bf(v.y) << 16);
    o.y = (uint32_t)f2bf(v.z) | ((uint32_t)f2bf(v.w) << 16);
    xbf[i] = o;
  }
}

__global__ void cvt_wt_kernel(const float* __restrict__ W, unsigned short* __restrict__ wt) {
  int id = blockIdx.x * 256 + threadIdx.x;   // 1048576 total
  int k = id >> 11, n = id & 2047;
  wt[n * 512 + k] = f2bf(W[id]);
}

// R fp32 [512][2048] -> Rq: rq[k8*2048+n] = 8 consecutive-k bf16 of column n
// (exactly an MFMA B-frag quad-chunk: element e of the bf16x8 is k = 8*k8+e).
__global__ void cvt_rq_kernel(const float* __restrict__ R, uint4* __restrict__ rq) {
  int id = blockIdx.x * 256 + threadIdx.x;   // 131072 = 64*2048
  int k8 = id >> 11, n = id & 2047;
  const float* base = R + (size_t)(k8 * 8) * 2048 + n;
  uint32_t d[4];
#pragma unroll
  for (int q = 0; q < 4; ++q) {
    uint32_t lo = f2bf(base[(2 * q) * 2048]);
    uint32_t hi = f2bf(base[(2 * q + 1) * 2048]);
    d[q] = lo | (hi << 16);
  }
  rq[id] = make_uint4(d[0], d[1], d[2], d[3]);
}

// Zero h buffers (hi+lo, both phases) and flags. Runs AFTER the GEMM
// (the region aliases the then-dead xbf staging buffer).
__global__ void init_kernel(uint4* __restrict__ hz, uint32_t* __restrict__ flags) {
  int id = blockIdx.x * 256 + threadIdx.x;
  if (id < 32768) hz[id] = make_uint4(0u, 0u, 0u, 0u);   // 512 KiB
  if (id < 1024) flags[id] = 0u;
}

// ------------------------------ front GEMM ----------------------------------

__device__ __forceinline__ void xg_store(float* C, size_t idx, float v) { C[idx] = v; }
__device__ __forceinline__ void xg_store(unsigned short* C, size_t idx, float v) { C[idx] = f2bf(v); }

template <typename XG>
__global__ __launch_bounds__(256, 2) void gemm_kernel(
    const unsigned short* __restrict__ A, const unsigned short* __restrict__ Bt,
    const float* __restrict__ bias, XG* __restrict__ C) {
  __shared__ __align__(16) unsigned short ldsA[128 * 72];
  __shared__ __align__(16) unsigned short ldsB[128 * 72];

  const int n0 = blockIdx.x * 128;
  const int m0 = blockIdx.y * 128;
  const int tid = threadIdx.x;
  const int lane = tid & 63;
  const int wave = tid >> 6;
  const int wm = wave >> 1, wn = wave & 1;
  const int l15 = lane & 15, quad = lane >> 4;
  const int seg = tid & 7, row0 = tid >> 3;

  floatx4 acc[4][4];
#pragma unroll
  for (int mi = 0; mi < 4; ++mi)
#pragma unroll
    for (int ni = 0; ni < 4; ++ni) acc[mi][ni] = (floatx4)0.0f;

  for (int k0 = 0; k0 < 512; k0 += 64) {
    __syncthreads();
#pragma unroll
    for (int it = 0; it < 4; ++it) {
      int row = row0 + it * 32;
      *(uint4*)&ldsA[row * 72 + seg * 8] =
          *(const uint4*)&A[(size_t)(m0 + row) * 512 + k0 + seg * 8];
      *(uint4*)&ldsB[row * 72 + seg * 8] =
          *(const uint4*)&Bt[(size_t)(n0 + row) * 512 + k0 + seg * 8];
    }
    __syncthreads();
#pragma unroll
    for (int kk = 0; kk < 2; ++kk) {
      bf16x8 af[4], bfv[4];
#pragma unroll
      for (int mi = 0; mi < 4; ++mi)
        af[mi] = *(const bf16x8*)&ldsA[(wm * 64 + mi * 16 + l15) * 72 + kk * 32 + quad * 8];
#pragma unroll
      for (int ni = 0; ni < 4; ++ni)
        bfv[ni] = *(const bf16x8*)&ldsB[(wn * 64 + ni * 16 + l15) * 72 + kk * 32 + quad * 8];
#pragma unroll
      for (int mi = 0; mi < 4; ++mi)
#pragma unroll
        for (int ni = 0; ni < 4; ++ni)
          acc[mi][ni] = __builtin_amdgcn_mfma_f32_16x16x32_bf16(af[mi], bfv[ni], acc[mi][ni], 0, 0, 0);
    }
  }

#pragma unroll
  for (int mi = 0; mi < 4; ++mi)
#pragma unroll
    for (int ni = 0; ni < 4; ++ni) {
      int gr = m0 + wm * 64 + mi * 16 + quad * 4;
      int gc = n0 + wn * 64 + ni * 16 + l15;
      float bv = bias[gc];
#pragma unroll
      for (int r = 0; r < 4; ++r)
        xg_store(C, (size_t)(gr + r) * 2048 + gc, acc[mi][ni][r] + bv);
    }
}

// ------------------------------ recurrence ----------------------------------

__device__ __forceinline__ float2 xg2(const float* p) { return *(const float2*)p; }
__device__ __forceinline__ float2 xg2(const unsigned short* p) {
  uint32_t v = *(const uint32_t*)p;
  return make_float2(bflo(v), bfhi(v));
}

__device__ __forceinline__ float sigf(float x) { return 1.0f / (1.0f + __expf(-x)); }
__device__ __forceinline__ float tanh_fast(float x) {
  float xx = fminf(fmaxf(x, -9.0f), 9.0f);
  float t = __expf(2.0f * xx);
  return (t - 1.0f) / (t + 1.0f);
}

// 64 persistent blocks x 512 threads (8 waves: 4 batch-groups x 2 col-groups).
// Block owns units [blk*8, blk*8+8) -> 32 gate cols. R frags in VGPRs.
// Double-buffer safety: a block writes buffer (t+1)&1 only after observing
// all flags >= t, i.e. every block finished step t-1 and thus finished
// READING buffer (t-1)&1 == (t+1)&1.
template <typename XG>
__global__ __launch_bounds__(512, 2) void lstm_rec_kernel(
    const uint4* __restrict__ Rq, const XG* __restrict__ xg,
    unsigned short* __restrict__ hbuf_hi, unsigned short* __restrict__ hbuf_lo,
    uint32_t* __restrict__ flags, float* __restrict__ out) {
  __shared__ __align__(16) float zbuf[128 * 36];   // z[b][col], stride 36

  const int blk = blockIdx.x;       // 0..63
  const int tid = threadIdx.x;
  const int lane = tid & 63;
  const int wave = tid >> 6;        // 0..7
  const int wm = wave >> 1;         // batch group (32 rows)
  const int wn = wave & 1;          // col group (16 cols)
  const int l15 = lane & 15;
  const int quad = lane >> 4;
  const int u0 = blk * 8;

  // ---- register-resident R slice: 16 B-frags for this wave's 16 cols ----
  const int cl = wn * 16 + l15;          // local col 0..31  (= unit*4 + gate)
  const int unit = cl >> 2;
  const int gate = cl & 3;
  const int gcol = gate * 512 + u0 + unit;
  bf16x8 rfrag[16];
#pragma unroll
  for (int kf = 0; kf < 16; ++kf)
    rfrag[kf] = *(const bf16x8*)&Rq[(size_t)(kf * 4 + quad) * 2048 + gcol];

  // gate-stage identity: thread -> (batch gb, local units gu, gu+1)
  const int gb = tid >> 2;
  const int gu = (tid & 3) * 2;
  float c0 = 0.0f, c1 = 0.0f;

  const size_t xg_base = (size_t)gb * 1024 * 2048 + u0 + gu;
  const size_t hoff = (size_t)gb * 512 + u0 + gu;

  for (int t = 0; t < 1024; ++t) {
    // prefetch this step's xg (read-only; safe to issue before the acquire)
    float2 xp0, xp1, xp2, xp3;
    {
      const XG* p = xg + xg_base + (size_t)t * 2048;
      xp0 = xg2(p);
      xp1 = xg2(p + 512);
      xp2 = xg2(p + 1024);
      xp3 = xg2(p + 1536);
    }

    // barrier: wait until every block has published h(t).
    // Relaxed coherent polls; ONE acquire fence after the spin.
    if (wave == 0) {
      if (t > 0) {
        int cap = 0;
        do {
          uint32_t f = __hip_atomic_load(&flags[lane * 16], __ATOMIC_RELAXED,
                                         __HIP_MEMORY_SCOPE_AGENT);
          if (f >= (uint32_t)t) break;
          __builtin_amdgcn_s_sleep(1);
        } while (++cap < 16384);   // bounded: wrong-but-visible beats a hang
      }
      __builtin_amdgcn_fence(__ATOMIC_ACQUIRE, "agent");
    }
    __syncthreads();

    // ---- z = h(t) @ Rslice  (hi + lo accumulate into same fp32 acc) ----
    const unsigned short* hh = hbuf_hi + ((t & 1) << 16);
    const unsigned short* hl = hbuf_lo + ((t & 1) << 16);
    const unsigned short* hrow0 = hh + (size_t)(wm * 32 + l15) * 512 + quad * 8;
    const unsigned short* hrow1 = hrow0 + 16 * 512;
    const unsigned short* lrow0 = hl + (size_t)(wm * 32 + l15) * 512 + quad * 8;
    const unsigned short* lrow1 = lrow0 + 16 * 512;

    floatx4 acc0 = (floatx4)0.0f, acc1 = (floatx4)0.0f;
    bf16x8 ah0 = *(const bf16x8*)(hrow0);
    bf16x8 ah1 = *(const bf16x8*)(hrow1);
    bf16x8 al0 = *(const bf16x8*)(lrow0);
    bf16x8 al1 = *(const bf16x8*)(lrow1);
    bf16x8 nh0, nh1, nl0, nl1;
#pragma unroll
    for (int kf = 0; kf < 16; ++kf) {
      if (kf < 15) {
        const int ko = (kf + 1) * 32;
        nh0 = *(const bf16x8*)(hrow0 + ko);
        nh1 = *(const bf16x8*)(hrow1 + ko);
        nl0 = *(const bf16x8*)(lrow0 + ko);
        nl1 = *(const bf16x8*)(lrow1 + ko);
      }
      acc0 = __builtin_amdgcn_mfma_f32_16x16x32_bf16(ah0, rfrag[kf], acc0, 0, 0, 0);
      acc1 = __builtin_amdgcn_mfma_f32_16x16x32_bf16(ah1, rfrag[kf], acc1, 0, 0, 0);
      acc0 = __builtin_amdgcn_mfma_f32_16x16x32_bf16(al0, rfrag[kf], acc0, 0, 0, 0);
      acc1 = __builtin_amdgcn_mfma_f32_16x16x32_bf16(al1, rfrag[kf], acc1, 0, 0, 0);
      ah0 = nh0; ah1 = nh1; al0 = nl0; al1 = nl1;
    }

    // stash z to LDS: C/D layout col=l15, row=quad*4+r
#pragma unroll
    for (int r = 0; r < 4; ++r) {
      zbuf[(wm * 32 + quad * 4 + r) * 36 + cl] = acc0[r];
      zbuf[(wm * 32 + 16 + quad * 4 + r) * 36 + cl] = acc1[r];
    }
    __syncthreads();

    // ---- gates for owned (gb, gu), (gb, gu+1) ----
    float4 z0 = *(const float4*)&zbuf[gb * 36 + gu * 4];       // i,f,g,o unit gu
    float4 z1 = *(const float4*)&zbuf[gb * 36 + gu * 4 + 4];   // unit gu+1

    float i0 = sigf(z0.x + xp0.x), f0 = sigf(z0.y + xp1.x);
    float g0 = tanh_fast(z0.z + xp2.x), o0 = sigf(z0.w + xp3.x);
    c0 = tanh_fast(f0 * c0 + i0 * g0);      // faithful quirk: tanh'd cell carried
    float h0 = o0 * c0;

    float i1 = sigf(z1.x + xp0.y), f1 = sigf(z1.y + xp1.y);
    float g1 = tanh_fast(z1.z + xp2.y), o1 = sigf(z1.w + xp3.y);
    c1 = tanh_fast(f1 * c1 + i1 * g1);
    float h1 = o1 * c1;

    // hi/lo split (bf16 pair ~ fp32), publish h(t+1) slice + out
    unsigned short h0h = f2bf(h0);
    unsigned short h1h = f2bf(h1);
    unsigned short h0l = f2bf(h0 - bf2f(h0h));
    unsigned short h1l = f2bf(h1 - bf2f(h1h));
    const int nb = ((t + 1) & 1) << 16;
    *(uint32_t*)(hbuf_hi + nb + hoff) = (uint32_t)h0h | ((uint32_t)h1h << 16);
    *(uint32_t*)(hbuf_lo + nb + hoff) = (uint32_t)h0l | ((uint32_t)h1l << 16);
    *(float2*)&out[((size_t)gb * 1024 + t) * 512 + u0 + gu] = make_float2(h0, h1);

    __syncthreads();   // all 512 threads' h stores acked (vmcnt drained)
    if (tid == 0) {
      __builtin_amdgcn_fence(__ATOMIC_RELEASE, "agent");   // XCD L2 writeback
      __hip_atomic_store(&flags[blk * 16], (uint32_t)(t + 1),
                         __ATOMIC_RELAXED, __HIP_MEMORY_SCOPE_AGENT);
    }
  }
}

// ------------------------------ launcher ------------------------------------

extern "C" void kernel_launch(void* const* d_in, const int* in_sizes, int n_in,
                              void* d_out, int out_size, void* d_ws, size_t ws_size,
                              hipStream_t stream) {
  const float* x = (const float*)d_in[0];     // [128,1024,512]
  const float* W = (const float*)d_in[1];     // [512,2048]
  const float* R = (const float*)d_in[2];     // [512,2048]
  const float* bias = (const float*)d_in[3];  // [2048]
  float* out = (float*)d_out;                 // [128,1024,512]

  char* ws = (char*)d_ws;
  const size_t off_xbf = 0;                   // 134,217,728 B  (x bf16; dead after GEMM)
  const size_t off_wt = 134217728;            //   2,097,152 B  (W^T bf16)
  const size_t off_rq = 136314880;            //   2,097,152 B  (R packed bf16)
  const size_t off_xg = 138412032;            //  xg: 1 GiB fp32 or 512 MiB bf16
  unsigned short* xbf = (unsigned short*)(ws + off_xbf);
  unsigned short* wt = (unsigned short*)(ws + off_wt);
  uint4* rq = (uint4*)(ws + off_rq);
  void* xgp = (void*)(ws + off_xg);

  // Persistent-recurrence state reuses the (then-dead) xbf region.
  unsigned short* hhi = (unsigned short*)(ws + 0);        // [2][128][512] bf16
  unsigned short* hlo = (unsigned short*)(ws + 262144);   // [2][128][512] bf16
  uint32_t* flg = (uint32_t*)(ws + 524288);               // 64 flags, 64B stride

  const bool xg_f32 = ws_size >= off_xg + 1073741824ull;
  const bool xg_bf16_fits = ws_size >= off_xg + 536870912ull;

  hipLaunchKernelGGL(cvt_x_kernel, dim3(2048), dim3(256), 0, stream,
                     (const float4*)x, (uint2*)xbf, 16777216);
  hipLaunchKernelGGL(cvt_wt_kernel, dim3(4096), dim3(256), 0, stream, W, wt);
  hipLaunchKernelGGL(cvt_rq_kernel, dim3(512), dim3(256), 0, stream, R, rq);

  if (xg_f32) {
    hipLaunchKernelGGL((gemm_kernel<float>), dim3(16, 1024), dim3(256), 0, stream,
                       xbf, wt, bias, (float*)xgp);
    hipLaunchKernelGGL(init_kernel, dim3(128), dim3(256), 0, stream,
                       (uint4*)(ws + 0), flg);
    hipLaunchKernelGGL((lstm_rec_kernel<float>), dim3(64), dim3(512), 0, stream,
                       rq, (const float*)xgp, hhi, hlo, flg, out);
  } else if (xg_bf16_fits) {
    hipLaunchKernelGGL((gemm_kernel<unsigned short>), dim3(16, 1024), dim3(256), 0, stream,
                       xbf, wt, bias, (unsigned short*)xgp);
    hipLaunchKernelGGL(init_kernel, dim3(128), dim3(256), 0, stream,
                       (uint4*)(ws + 0), flg);
    hipLaunchKernelGGL((lstm_rec_kernel<unsigned short>), dim3(64), dim3(512), 0, stream,
                       rq, (const unsigned short*)xgp, hhi, hlo, flg, out);
  }
  // If neither fits, output stays poisoned -> visible failure (ws too small).
}